// Round 14
// baseline (445.680 us; speedup 1.0000x reference)
//
#include <hip/hip_runtime.h>
#include <hip/hip_bf16.h>
#include <math.h>

#define NB 32
#define NQ 2048
#define NK 512
#define NE 16
#define NH 32
#define NL 20
#define NHID 50
#define NO 41

#define LOG2E 1.4426950408889634f
#define TWO_LOG2E 2.8853900817779268f

// ws layout (floats):
// gi   : [64][512][96] @ 0        (3,145,728)  OVERLAID with att (gru before attn)
// att  : [65536][64]   @ 0        (4,194,304)  normalized P@val (pre-Wv)
// val  : [32][512][64] @ 4194304  (1,048,576)
// ktab : [512][16]     @ 5242880  (8,192)
// w1p  : [50][64]      @ 5251072  (3,200)      W1 @ Wv
// b1p  : [50]          @ 5254272  (64)         b1 + W1 @ bv
// total ~21.0 MB (proven size)

typedef __attribute__((ext_vector_type(2))) float f32x2;

__device__ __forceinline__ float bperm(int lane, float v) {
  return __builtin_bit_cast(
      float, __builtin_amdgcn_ds_bpermute(lane << 2, __builtin_bit_cast(int, v)));
}

// blocks 0-1: k-table. block 2: fold Wv into W1.
__global__ __launch_bounds__(256) void prep_kernel(
    const float* __restrict__ refq, const float* __restrict__ Wk,
    const float* __restrict__ bk,
    const float* __restrict__ Wv, const float* __restrict__ bv,
    const float* __restrict__ W1, const float* __restrict__ b1,
    float* __restrict__ ktab, float* __restrict__ w1p,
    float* __restrict__ b1p) {
  const int tid = threadIdx.x;
  if (blockIdx.x < 2) {
    const int r = blockIdx.x * 256 + tid;
    const float divs[8] = {1.0f, 0.74989421f, 0.56234133f, 0.42169650f,
                           0.31622777f, 0.23713737f, 0.17782794f, 0.13335214f};
    float pos = refq[r];
    float emb[NE];
#pragma unroll
    for (int m = 0; m < 8; ++m) {
      float a = 48.0f * pos * divs[m];
      emb[2 * m] = sinf(a);
      emb[2 * m + 1] = cosf(a);
    }
#pragma unroll
    for (int e = 0; e < NE; ++e) {
      float acc = bk[e];
#pragma unroll
      for (int i = 0; i < NE; ++i) acc += emb[i] * Wk[e * NE + i];
      ktab[r * NE + e] = acc;
    }
  } else {
    for (int e = tid; e < NHID * 64; e += 256) {
      const int o = e >> 6, i = e & 63;
      float acc = 0.f;
#pragma unroll 4
      for (int d = 0; d < 64; ++d) acc += W1[o * 64 + d] * Wv[d * 64 + i];
      w1p[e] = acc;
    }
    if (tid < NHID) {
      float acc = b1[tid];
#pragma unroll 4
      for (int d = 0; d < 64; ++d) acc += W1[tid * 64 + d] * bv[d];
      b1p[tid] = acc;
    }
  }
}

// Input-side gates, fully parallel; pre-scaled for exp2-based activations.
__global__ __launch_bounds__(256) void prep_gi_kernel(
    const float* __restrict__ z,
    const float* __restrict__ Wih_f, const float* __restrict__ bih_f,
    const float* __restrict__ bhh_f,
    const float* __restrict__ Wih_b, const float* __restrict__ bih_b,
    const float* __restrict__ bhh_b, float* __restrict__ gi) {
  const int row = blockIdx.x * 256 + threadIdx.x;  // chain*512 + t
  const int c = row >> 9, t = row & 511;
  const int dir = c >> 5, b = c & 31;
  const float* __restrict__ Wih = dir ? Wih_b : Wih_f;
  const float* __restrict__ bih = dir ? bih_b : bih_f;
  const float* __restrict__ bhh = dir ? bhh_b : bhh_f;
  const float* __restrict__ zr = z + ((size_t)b * NK + t) * NL;
  float x[NL];
#pragma unroll
  for (int i = 0; i < NL; ++i) x[i] = zr[i];
  float* __restrict__ go = gi + (size_t)row * 96;
  for (int g = 0; g < 96; ++g) {
    float acc = bih[g] + (g < 64 ? bhh[g] : 0.f);
#pragma unroll
    for (int i = 0; i < NL; ++i) acc += x[i] * Wih[g * NL + i];
    go[g] = acc * (g < 64 ? LOG2E : TWO_LOG2E);
  }
}

// Serial GRU with 2-way TEMPORAL interleave: 4 chains per block (2 spatial x
// 2 temporal), 16 blocks. Phase-B's DS round hides under phase-A's compute
// and vice versa; weights are shared (same dir for all 4 chains per block).
__global__ __launch_bounds__(64) void gru_kernel(
    const float* __restrict__ gi,
    const float* __restrict__ Whh_f, const float* __restrict__ bhh_f,
    const float* __restrict__ Whh_b, const float* __restrict__ bhh_b,
    float* __restrict__ val) {
  __shared__ __align__(16) float hbufA[64];
  __shared__ __align__(16) float hbufB[64];
  const int l = threadIdx.x;
  const int j = l & 31, half = l >> 5;
  const int cbase = blockIdx.x * 4;       // 4|32 => all 4 chains same dir
  const int dir = cbase >> 5;
  const int c0 = cbase + half, c1 = cbase + 2 + half;
  const int b0 = c0 & 31, b1 = c1 & 31;
  const int hb = half * 32;
  const float* __restrict__ Whh = dir ? Whh_b : Whh_f;
  const float* __restrict__ bhh = dir ? bhh_b : bhh_f;

  // weights pre-scaled: r,z x log2e; n x 2*log2e (gi scaled to match)
  f32x2 wr[16], wz[16], wn[16];
#pragma unroll
  for (int i = 0; i < 16; ++i) {
    wr[i] = f32x2{Whh[j * 32 + 2 * i], Whh[j * 32 + 2 * i + 1]} * LOG2E;
    wz[i] = f32x2{Whh[(j + 32) * 32 + 2 * i], Whh[(j + 32) * 32 + 2 * i + 1]} *
            LOG2E;
    wn[i] = f32x2{Whh[(j + 64) * 32 + 2 * i], Whh[(j + 64) * 32 + 2 * i + 1]} *
            TWO_LOG2E;
  }
  const float bhn = bhh[j + 64] * TWO_LOG2E;
  float hA = 0.f, hB = 0.f;
  hbufA[l] = 0.f;
  hbufB[l] = 0.f;

  const float* __restrict__ gicA = gi + (size_t)c0 * NK * 96;
  const float* __restrict__ gicB = gi + (size_t)c1 * NK * 96;
  const int gstart = dir ? (NK - 1) * 96 : 0;
  const int gstride = dir ? -96 : 96;
  float* __restrict__ vpA =
      val + ((size_t)b0 * NK + (dir ? NK - 1 : 0)) * 64 + dir * 32 + j;
  float* __restrict__ vpB =
      val + ((size_t)b1 * NK + (dir ? NK - 1 : 0)) * 64 + dir * 32 + j;
  const int vstride = dir ? -64 : 64;

  int gA = gstart, gB = gstart;
  auto glA = [&](float& r, float& z, float& n) {
    const float* p = gicA + gA;
    r = p[j]; z = p[32 + j]; n = p[64 + j];
    gA += gstride;
  };
  auto glB = [&](float& r, float& z, float& n) {
    const float* p = gicB + gB;
    r = p[j]; z = p[32 + j]; n = p[64 + j];
    gB += gstride;
  };

  float rA0, zA0, nA0, rA1, zA1, nA1, rA2, zA2, nA2, rA3, zA3, nA3;
  float rB0, zB0, nB0, rB1, zB1, nB1, rB2, zB2, nB2, rB3, zB3, nB3;
  glA(rA0, zA0, nA0); glA(rA1, zA1, nA1);
  glA(rA2, zA2, nA2); glA(rA3, zA3, nA3);
  glB(rB0, zB0, nB0); glB(rB1, zB1, nB1);
  glB(rB2, zB2, nB2); glB(rB3, zB3, nB3);

  auto dot3 = [&](const f32x2 (&hv)[16], float& sr, float& sz, float& sn) {
    f32x2 s0 = {0.f, 0.f}, s1 = {0.f, 0.f}, s2 = {0.f, 0.f};
    f32x2 s3 = {0.f, 0.f}, s4 = {0.f, 0.f}, s5 = {0.f, 0.f};
#pragma unroll
    for (int t = 0; t < 8; ++t) {
      s0 = __builtin_elementwise_fma(wr[t], hv[t], s0);
      s1 = __builtin_elementwise_fma(wz[t], hv[t], s1);
      s2 = __builtin_elementwise_fma(wn[t], hv[t], s2);
      s3 = __builtin_elementwise_fma(wr[8 + t], hv[8 + t], s3);
      s4 = __builtin_elementwise_fma(wz[8 + t], hv[8 + t], s4);
      s5 = __builtin_elementwise_fma(wn[8 + t], hv[8 + t], s5);
    }
    sr = (s0.x + s0.y) + (s3.x + s3.y);
    sz = (s1.x + s1.y) + (s4.x + s4.y);
    sn = (s2.x + s2.y) + (s5.x + s5.y);
  };

  auto stepAB = [&](bool pf, float& grA, float& gzA, float& gnA,
                    float& grB, float& gzB, float& gnB) {
    const float iAr = grA, iAz = gzA, iAn = gnA;
    const float iBr = grB, iBz = gzB, iBn = gnB;
    if (pf) { glA(grA, gzA, gnA); glB(grB, gzB, gnB); }
    // issue A's DS round, then B's: B's latency hides under A's compute
    hbufA[l] = hA;  // same-wave LDS in-order (proven rounds 4-13)
    f32x2 hvA[16];
#pragma unroll
    for (int t = 0; t < 4; ++t) {
      const float4 q0 = *(const float4*)&hbufA[hb + t * 8];
      const float4 q1 = *(const float4*)&hbufA[hb + t * 8 + 4];
      hvA[t * 4 + 0] = f32x2{q0.x, q0.y};
      hvA[t * 4 + 1] = f32x2{q0.z, q0.w};
      hvA[t * 4 + 2] = f32x2{q1.x, q1.y};
      hvA[t * 4 + 3] = f32x2{q1.z, q1.w};
    }
    hbufB[l] = hB;
    f32x2 hvB[16];
#pragma unroll
    for (int t = 0; t < 4; ++t) {
      const float4 q0 = *(const float4*)&hbufB[hb + t * 8];
      const float4 q1 = *(const float4*)&hbufB[hb + t * 8 + 4];
      hvB[t * 4 + 0] = f32x2{q0.x, q0.y};
      hvB[t * 4 + 1] = f32x2{q0.z, q0.w};
      hvB[t * 4 + 2] = f32x2{q1.x, q1.y};
      hvB[t * 4 + 3] = f32x2{q1.z, q1.w};
    }
    // compute A
    float srA, szA, snA;
    dot3(hvA, srA, szA, snA);
    const float rgA =
        __builtin_amdgcn_rcpf(1.0f + __builtin_amdgcn_exp2f(-(iAr + srA)));
    const float ugA =
        __builtin_amdgcn_rcpf(1.0f + __builtin_amdgcn_exp2f(-(iAz + szA)));
    const float ngA =
        1.0f - 2.0f * __builtin_amdgcn_rcpf(
                          __builtin_amdgcn_exp2f(iAn + rgA * (snA + bhn)) + 1.0f);
    hA = ngA + ugA * (hA - ngA);
    *vpA = hA;
    vpA += vstride;
    // compute B
    float srB, szB, snB;
    dot3(hvB, srB, szB, snB);
    const float rgB =
        __builtin_amdgcn_rcpf(1.0f + __builtin_amdgcn_exp2f(-(iBr + srB)));
    const float ugB =
        __builtin_amdgcn_rcpf(1.0f + __builtin_amdgcn_exp2f(-(iBz + szB)));
    const float ngB =
        1.0f - 2.0f * __builtin_amdgcn_rcpf(
                          __builtin_amdgcn_exp2f(iBn + rgB * (snB + bhn)) + 1.0f);
    hB = ngB + ugB * (hB - ngB);
    *vpB = hB;
    vpB += vstride;
  };
  for (int s = 0; s < NK; s += 4) {
    stepAB(s + 4 < NK, rA0, zA0, nA0, rB0, zB0, nB0);
    stepAB(s + 5 < NK, rA1, zA1, nA1, rB1, zB1, nB1);
    stepAB(s + 6 < NK, rA2, zA2, nA2, rB2, zB2, nB2);
    stepAB(s + 7 < NK, rA3, zA3, nA3, rB3, zB3, nB3);
  }
}

// R=8 attention v3: kt read straight from global (L1/L2 broadcast — no LDS
// staging) => LDS 18 KB => 8 blocks/CU = 32 waves/CU. exp2 with pre-scaled q.
__global__ __launch_bounds__(256) void attn_core_kernel(
    const float* __restrict__ tsteps, const float* __restrict__ ktab,
    const float* __restrict__ val,
    const float* __restrict__ Wq, const float* __restrict__ bq,
    float* __restrict__ att) {
  __shared__ __align__(16) float cbuf[4][64][16];    // 16 KB combine buffer
  __shared__ float lbuf[4][64];                      // 1 KB lsum partials
  __shared__ float wqs[NE * NE];
  __shared__ float bqs[NE];
  const int tid = threadIdx.x;
  for (int i = tid; i < NE * NE; i += 256) wqs[i] = Wq[i];
  if (tid < NE) bqs[tid] = bq[tid];
  __syncthreads();

  const int lane = tid & 63;
  const int g = lane >> 3;      // group 0..7
  const int r8 = lane & 7;      // row-in-group for scoring; d-eighth for acc
  const int wave = tid >> 6;    // k-quarter owner
  const int rowbase = blockIdx.x * 64 + g * 8;
  const int myrow = rowbase + r8;
  const int b = myrow >> 11;    // uniform per block (64-row span, 64|2048)

  const float pos = tsteps[myrow];
  const float divs[8] = {1.0f, 0.74989421f, 0.56234133f, 0.42169650f,
                         0.31622777f, 0.23713737f, 0.17782794f, 0.13335214f};
  float emb[NE];
#pragma unroll
  for (int m = 0; m < 8; ++m) {
    float a = 48.0f * pos * divs[m];
    emb[2 * m] = sinf(a);
    emb[2 * m + 1] = cosf(a);
  }
  float q[NE];
#pragma unroll
  for (int e = 0; e < NE; ++e) {
    float acc = bqs[e];
#pragma unroll
    for (int i = 0; i < NE; ++i) acc += emb[i] * wqs[e * NE + i];
    q[e] = acc * (0.25f * LOG2E);  // fold 1/sqrt(E) and log2e (exp2 direct)
  }
  const int lb = lane & ~7;  // group's lane 0
  const float* __restrict__ vb = val + (size_t)b * NK * 64;

  float acc[8][8];
#pragma unroll
  for (int m = 0; m < 8; ++m)
#pragma unroll
    for (int d = 0; d < 8; ++d) acc[m][d] = 0.f;
  float lsum = 0.f;

#pragma unroll
  for (int kb = 0; kb < 2; ++kb) {
    const int khi = (wave << 1) | kb;   // this wave's k-block (uniform)
#pragma unroll 2
    for (int i = 0; i < 64; ++i) {
      const int ii = (i + g * 8) & 63;  // group stagger: distinct rows/instr
      const int k = (khi << 6) | ii;
      const float4* kr = (const float4*)(ktab + (size_t)k * NE);
      const float4 k0 = kr[0], k1 = kr[1], k2 = kr[2], k3 = kr[3];
      float s;
      s  = q[0] * k0.x + q[1] * k0.y + q[2] * k0.z + q[3] * k0.w;
      s += q[4] * k1.x + q[5] * k1.y + q[6] * k1.z + q[7] * k1.w;
      s += q[8] * k2.x + q[9] * k2.y + q[10] * k2.z + q[11] * k2.w;
      s += q[12] * k3.x + q[13] * k3.y + q[14] * k3.z + q[15] * k3.w;
      const float p = __builtin_amdgcn_exp2f(s);  // scores O(1): no max-sub
      lsum += p;
      const float* vr = vb + (size_t)k * 64 + r8 * 8;
      const float4 va = *(const float4*)(vr);
      const float4 vb4 = *(const float4*)(vr + 4);
      float pm[8];
#pragma unroll
      for (int m = 0; m < 8; ++m) pm[m] = bperm(lb + m, p);
#pragma unroll
      for (int m = 0; m < 8; ++m) {
        acc[m][0] += pm[m] * va.x;  acc[m][1] += pm[m] * va.y;
        acc[m][2] += pm[m] * va.z;  acc[m][3] += pm[m] * va.w;
        acc[m][4] += pm[m] * vb4.x; acc[m][5] += pm[m] * vb4.y;
        acc[m][6] += pm[m] * vb4.z; acc[m][7] += pm[m] * vb4.w;
      }
    }
  }

  // cross-wave combine: 4 partials per (row, dim); lsum totals once.
  lbuf[wave][lane] = lsum;
  float lt = 0.f;
  float* ob = att + (size_t)rowbase * 64 + r8 * 8;
#pragma unroll
  for (int mm = 0; mm < 8; mm += 2) {
    *(float4*)&cbuf[wave][lane][0] =
        make_float4(acc[mm][0], acc[mm][1], acc[mm][2], acc[mm][3]);
    *(float4*)&cbuf[wave][lane][4] =
        make_float4(acc[mm][4], acc[mm][5], acc[mm][6], acc[mm][7]);
    *(float4*)&cbuf[wave][lane][8] =
        make_float4(acc[mm + 1][0], acc[mm + 1][1], acc[mm + 1][2],
                    acc[mm + 1][3]);
    *(float4*)&cbuf[wave][lane][12] =
        make_float4(acc[mm + 1][4], acc[mm + 1][5], acc[mm + 1][6],
                    acc[mm + 1][7]);
    __syncthreads();
    if (mm == 0)
      lt = lbuf[0][lane] + lbuf[1][lane] + lbuf[2][lane] + lbuf[3][lane];
    if (wave == 0) {
      float s[16];
#pragma unroll
      for (int d4 = 0; d4 < 4; ++d4) {
        const float4 c0 = *(const float4*)&cbuf[0][lane][d4 * 4];
        const float4 c1 = *(const float4*)&cbuf[1][lane][d4 * 4];
        const float4 c2 = *(const float4*)&cbuf[2][lane][d4 * 4];
        const float4 c3 = *(const float4*)&cbuf[3][lane][d4 * 4];
        s[d4 * 4 + 0] = c0.x + c1.x + c2.x + c3.x;
        s[d4 * 4 + 1] = c0.y + c1.y + c2.y + c3.y;
        s[d4 * 4 + 2] = c0.z + c1.z + c2.z + c3.z;
        s[d4 * 4 + 3] = c0.w + c1.w + c2.w + c3.w;
      }
      const float im0 = 1.0f / bperm(lb + mm, lt);
      const float im1 = 1.0f / bperm(lb + mm + 1, lt);
      *(float4*)(ob + mm * 64) =
          make_float4(s[0] * im0, s[1] * im0, s[2] * im0, s[3] * im0);
      *(float4*)(ob + mm * 64 + 4) =
          make_float4(s[4] * im0, s[5] * im0, s[6] * im0, s[7] * im0);
      *(float4*)(ob + (mm + 1) * 64) =
          make_float4(s[8] * im1, s[9] * im1, s[10] * im1, s[11] * im1);
      *(float4*)(ob + (mm + 1) * 64 + 4) =
          make_float4(s[12] * im1, s[13] * im1, s[14] * im1, s[15] * im1);
    }
    __syncthreads();
  }
}

// Per-row MLP on folded weights: out = W2 @ relu(W1' @ ar + b1') + b2.
__global__ __launch_bounds__(256) void mlp_kernel(
    const float* __restrict__ att,
    const float* __restrict__ w1p, const float* __restrict__ b1p,
    const float* __restrict__ W2, const float* __restrict__ b2,
    float* __restrict__ out) {
  __shared__ __align__(16) float w1s[NHID * 64];   // 12.8 KB
  __shared__ __align__(16) float w2s[NO * NHID];   // 8.2 KB
  __shared__ float b1s[NHID], b2s[NO];
  const int tid = threadIdx.x;
  for (int i = tid; i < NHID * 64; i += 256) w1s[i] = w1p[i];
  for (int i = tid; i < NO * NHID; i += 256) w2s[i] = W2[i];
  if (tid < NHID) b1s[tid] = b1p[tid];
  if (tid < NO) b2s[tid] = b2[tid];
  __syncthreads();

  const int row = blockIdx.x * 256 + tid;
  float ar[64];
  const float4* a4 = (const float4*)(att + (size_t)row * 64);
#pragma unroll
  for (int d4 = 0; d4 < 16; ++d4) {
    float4 v = a4[d4];
    ar[d4 * 4 + 0] = v.x;
    ar[d4 * 4 + 1] = v.y;
    ar[d4 * 4 + 2] = v.z;
    ar[d4 * 4 + 3] = v.w;
  }
  float outv[NO];
#pragma unroll
  for (int oo = 0; oo < NO; ++oo) outv[oo] = b2s[oo];
#pragma unroll 2
  for (int o = 0; o < NHID; ++o) {
    float acc = b1s[o];
    const float4* w4 = (const float4*)&w1s[o * 64];
#pragma unroll
    for (int i4 = 0; i4 < 16; ++i4) {
      float4 ww = w4[i4];
      acc += ar[i4 * 4 + 0] * ww.x + ar[i4 * 4 + 1] * ww.y +
             ar[i4 * 4 + 2] * ww.z + ar[i4 * 4 + 3] * ww.w;
    }
    const float hv = fmaxf(acc, 0.f);
#pragma unroll
    for (int oo = 0; oo < NO; ++oo) outv[oo] += hv * w2s[oo * NHID + o];
  }
  float* orow = out + (size_t)row * NO;
#pragma unroll
  for (int oo = 0; oo < NO; ++oo) orow[oo] = outv[oo];
}

extern "C" void kernel_launch(void* const* d_in, const int* in_sizes, int n_in,
                              void* d_out, int out_size, void* d_ws, size_t ws_size,
                              hipStream_t stream) {
  const float* z = (const float*)d_in[0];
  const float* ts = (const float*)d_in[1];
  const float* refq = (const float*)d_in[2];
  const float* Wih_f = (const float*)d_in[3];
  const float* Whh_f = (const float*)d_in[4];
  const float* bih_f = (const float*)d_in[5];
  const float* bhh_f = (const float*)d_in[6];
  const float* Wih_b = (const float*)d_in[7];
  const float* Whh_b = (const float*)d_in[8];
  const float* bih_b = (const float*)d_in[9];
  const float* bhh_b = (const float*)d_in[10];
  const float* Wq = (const float*)d_in[11];
  const float* bq = (const float*)d_in[12];
  const float* Wk = (const float*)d_in[13];
  const float* bk = (const float*)d_in[14];
  const float* Wv = (const float*)d_in[15];
  const float* bv = (const float*)d_in[16];
  const float* W1 = (const float*)d_in[17];
  const float* b1 = (const float*)d_in[18];
  const float* W2 = (const float*)d_in[19];
  const float* b2 = (const float*)d_in[20];

  float* ws = (float*)d_ws;
  float* gi = ws;               // 3,145,728 (overlaid with att)
  float* att = ws;              // 4,194,304
  float* val = ws + 4194304;    // 1,048,576
  float* ktab = ws + 5242880;   // 8,192
  float* w1p = ws + 5251072;    // 3,200
  float* b1p = ws + 5254272;    // 64
  float* out = (float*)d_out;

  prep_kernel<<<3, 256, 0, stream>>>(refq, Wk, bk, Wv, bv, W1, b1,
                                     ktab, w1p, b1p);
  prep_gi_kernel<<<128, 256, 0, stream>>>(z, Wih_f, bih_f, bhh_f,
                                          Wih_b, bih_b, bhh_b, gi);
  gru_kernel<<<16, 64, 0, stream>>>(gi, Whh_f, bhh_f, Whh_b, bhh_b, val);
  attn_core_kernel<<<1024, 256, 0, stream>>>(ts, ktab, val, Wq, bq, att);
  mlp_kernel<<<256, 256, 0, stream>>>(att, w1p, b1p, W2, b2, out);
}

// Round 15
// 348.496 us; speedup vs baseline: 1.2789x; 1.2789x over previous
//
#include <hip/hip_runtime.h>
#include <hip/hip_bf16.h>
#include <math.h>

#define NB 32
#define NQ 2048
#define NK 512
#define NE 16
#define NH 32
#define NL 20
#define NHID 50
#define NO 41

#define LOG2E 1.4426950408889634f
#define TWO_LOG2E 2.8853900817779268f

// ws layout (floats):
// gi   : [64][512][96] @ 0        (3,145,728)  OVERLAID with att (gru before attn)
// att  : [65536][64]   @ 0        (4,194,304)  normalized P@val (pre-Wv)
// val  : [32][512][64] @ 4194304  (1,048,576)
// ktab : [512][16]     @ 5242880  (8,192)
// w1p  : [50][64]      @ 5251072  (3,200)      W1 @ Wv
// b1p  : [50]          @ 5254272  (64)         b1 + W1 @ bv
// total ~21.0 MB (proven size)

typedef __attribute__((ext_vector_type(2))) float f32x2;

__device__ __forceinline__ float bperm(int lane, float v) {
  return __builtin_bit_cast(
      float, __builtin_amdgcn_ds_bpermute(lane << 2, __builtin_bit_cast(int, v)));
}

// blocks 0-1: k-table. block 2: fold Wv into W1.
__global__ __launch_bounds__(256) void prep_kernel(
    const float* __restrict__ refq, const float* __restrict__ Wk,
    const float* __restrict__ bk,
    const float* __restrict__ Wv, const float* __restrict__ bv,
    const float* __restrict__ W1, const float* __restrict__ b1,
    float* __restrict__ ktab, float* __restrict__ w1p,
    float* __restrict__ b1p) {
  const int tid = threadIdx.x;
  if (blockIdx.x < 2) {
    const int r = blockIdx.x * 256 + tid;
    const float divs[8] = {1.0f, 0.74989421f, 0.56234133f, 0.42169650f,
                           0.31622777f, 0.23713737f, 0.17782794f, 0.13335214f};
    float pos = refq[r];
    float emb[NE];
#pragma unroll
    for (int m = 0; m < 8; ++m) {
      float a = 48.0f * pos * divs[m];
      emb[2 * m] = sinf(a);
      emb[2 * m + 1] = cosf(a);
    }
#pragma unroll
    for (int e = 0; e < NE; ++e) {
      float acc = bk[e];
#pragma unroll
      for (int i = 0; i < NE; ++i) acc += emb[i] * Wk[e * NE + i];
      ktab[r * NE + e] = acc;
    }
  } else {
    for (int e = tid; e < NHID * 64; e += 256) {
      const int o = e >> 6, i = e & 63;
      float acc = 0.f;
#pragma unroll 4
      for (int d = 0; d < 64; ++d) acc += W1[o * 64 + d] * Wv[d * 64 + i];
      w1p[e] = acc;
    }
    if (tid < NHID) {
      float acc = b1[tid];
#pragma unroll 4
      for (int d = 0; d < 64; ++d) acc += W1[tid * 64 + d] * bv[d];
      b1p[tid] = acc;
    }
  }
}

// Input-side gates, fully parallel; pre-scaled for exp2-based activations.
__global__ __launch_bounds__(256) void prep_gi_kernel(
    const float* __restrict__ z,
    const float* __restrict__ Wih_f, const float* __restrict__ bih_f,
    const float* __restrict__ bhh_f,
    const float* __restrict__ Wih_b, const float* __restrict__ bih_b,
    const float* __restrict__ bhh_b, float* __restrict__ gi) {
  const int row = blockIdx.x * 256 + threadIdx.x;  // chain*512 + t
  const int c = row >> 9, t = row & 511;
  const int dir = c >> 5, b = c & 31;
  const float* __restrict__ Wih = dir ? Wih_b : Wih_f;
  const float* __restrict__ bih = dir ? bih_b : bih_f;
  const float* __restrict__ bhh = dir ? bhh_b : bhh_f;
  const float* __restrict__ zr = z + ((size_t)b * NK + t) * NL;
  float x[NL];
#pragma unroll
  for (int i = 0; i < NL; ++i) x[i] = zr[i];
  float* __restrict__ go = gi + (size_t)row * 96;
  for (int g = 0; g < 96; ++g) {
    float acc = bih[g] + (g < 64 ? bhh[g] : 0.f);
#pragma unroll
    for (int i = 0; i < NL; ++i) acc += x[i] * Wih[g * NL + i];
    go[g] = acc * (g < 64 ? LOG2E : TWO_LOG2E);
  }
}

// Serial GRU (round-13, PASSED at 134 us): 2 chains per wave, full 32-dots,
// ONE DS round per step, exp2-folded activations, pk-FMA, pointer-walked IO.
__global__ __launch_bounds__(64) void gru_kernel(
    const float* __restrict__ gi,
    const float* __restrict__ Whh_f, const float* __restrict__ bhh_f,
    const float* __restrict__ Whh_b, const float* __restrict__ bhh_b,
    float* __restrict__ val) {
  __shared__ __align__(16) float hbuf[64];  // [chain-half][32]
  const int l = threadIdx.x;
  const int j = l & 31, half = l >> 5;
  const int c = blockIdx.x * 2 + half;   // 2|32 => both halves same dir
  const int dir = c >> 5, b = c & 31;
  const int hb = half * 32;
  const float* __restrict__ Whh = dir ? Whh_b : Whh_f;
  const float* __restrict__ bhh = dir ? bhh_b : bhh_f;

  // weights pre-scaled: r,z x log2e; n x 2*log2e (gi scaled to match)
  f32x2 wr[16], wz[16], wn[16];
#pragma unroll
  for (int i = 0; i < 16; ++i) {
    wr[i] = f32x2{Whh[j * 32 + 2 * i], Whh[j * 32 + 2 * i + 1]} * LOG2E;
    wz[i] = f32x2{Whh[(j + 32) * 32 + 2 * i], Whh[(j + 32) * 32 + 2 * i + 1]} *
            LOG2E;
    wn[i] = f32x2{Whh[(j + 64) * 32 + 2 * i], Whh[(j + 64) * 32 + 2 * i + 1]} *
            TWO_LOG2E;
  }
  const float bhn = bhh[j + 64] * TWO_LOG2E;
  float h = 0.f;
  hbuf[l] = 0.f;

  const float* __restrict__ gic = gi + (size_t)c * NK * 96;
  const int gstart = dir ? (NK - 1) * 96 : 0;
  const int gstride = dir ? -96 : 96;
  float* __restrict__ vp =
      val + ((size_t)b * NK + (dir ? NK - 1 : 0)) * 64 + dir * 32 + j;
  const int vstride = dir ? -64 : 64;

  float r0, z0, n0, r1, z1, n1, r2, z2, n2, r3, z3, n3;
  int gidx = gstart;
  auto giload = [&](float& gr, float& gz, float& gn) {
    const float* p = gic + gidx;
    gr = p[j];
    gz = p[32 + j];
    gn = p[64 + j];
    gidx += gstride;
  };
  giload(r0, z0, n0);
  giload(r1, z1, n1);
  giload(r2, z2, n2);
  giload(r3, z3, n3);

  auto step = [&](bool pf, float& gr, float& gz, float& gn) {
    const float gir = gr, giz = gz, gin = gn;
    if (pf) giload(gr, gz, gn);  // global prefetch (vmcnt queue)
    hbuf[l] = h;  // same-wave LDS is in-order (proven rounds 4-13)
    f32x2 hv[16];
#pragma unroll
    for (int t = 0; t < 4; ++t) {
      const float4 hq = *(const float4*)&hbuf[hb + t * 8];
      const float4 hq2 = *(const float4*)&hbuf[hb + t * 8 + 4];
      hv[t * 4 + 0] = f32x2{hq.x, hq.y};
      hv[t * 4 + 1] = f32x2{hq.z, hq.w};
      hv[t * 4 + 2] = f32x2{hq2.x, hq2.y};
      hv[t * 4 + 3] = f32x2{hq2.z, hq2.w};
    }
    f32x2 sr2 = {0.f, 0.f}, sz2 = {0.f, 0.f}, sn2 = {0.f, 0.f};
    f32x2 sr3 = {0.f, 0.f}, sz3 = {0.f, 0.f}, sn3 = {0.f, 0.f};
#pragma unroll
    for (int t = 0; t < 8; ++t) {
      sr2 = __builtin_elementwise_fma(wr[t], hv[t], sr2);
      sz2 = __builtin_elementwise_fma(wz[t], hv[t], sz2);
      sn2 = __builtin_elementwise_fma(wn[t], hv[t], sn2);
      sr3 = __builtin_elementwise_fma(wr[8 + t], hv[8 + t], sr3);
      sz3 = __builtin_elementwise_fma(wz[8 + t], hv[8 + t], sz3);
      sn3 = __builtin_elementwise_fma(wn[8 + t], hv[8 + t], sn3);
    }
    const float sr = (sr2.x + sr2.y) + (sr3.x + sr3.y);
    const float sz = (sz2.x + sz2.y) + (sz3.x + sz3.y);
    const float sn = (sn2.x + sn2.y) + (sn3.x + sn3.y);
    const float rg =
        __builtin_amdgcn_rcpf(1.0f + __builtin_amdgcn_exp2f(-(gir + sr)));
    const float ug =
        __builtin_amdgcn_rcpf(1.0f + __builtin_amdgcn_exp2f(-(giz + sz)));
    const float ng =
        1.0f - 2.0f * __builtin_amdgcn_rcpf(
                          __builtin_amdgcn_exp2f(gin + rg * (sn + bhn)) + 1.0f);
    h = ng + ug * (h - ng);
    *vp = h;
    vp += vstride;
  };
  for (int s = 0; s < NK; s += 4) {
    step(s + 4 < NK, r0, z0, n0);
    step(s + 5 < NK, r1, z1, n1);
    step(s + 6 < NK, r2, z2, n2);
    step(s + 7 < NK, r3, z3, n3);
  }
}

// R=8 attention v4: p-share via per-wave LDS slot (1 ds_write + 2 broadcast
// ds_read_b128) instead of 8 ds_bpermute — DS ops/iter 8 -> 3. kt from
// global (L1/L2 broadcast, r14-neutral), 4 waves/block over k-quarters,
// LDS combine (r12-proven).
__global__ __launch_bounds__(256) void attn_core_kernel(
    const float* __restrict__ tsteps, const float* __restrict__ ktab,
    const float* __restrict__ val,
    const float* __restrict__ Wq, const float* __restrict__ bq,
    float* __restrict__ att) {
  __shared__ __align__(16) float cbuf[4][64][16];    // 16 KB combine buffer
  __shared__ __align__(16) float pbuf[256];          // 1 KB p-share (per wave)
  __shared__ float lbuf[4][64];                      // 1 KB lsum partials
  __shared__ float wqs[NE * NE];
  __shared__ float bqs[NE];
  const int tid = threadIdx.x;
  for (int i = tid; i < NE * NE; i += 256) wqs[i] = Wq[i];
  if (tid < NE) bqs[tid] = bq[tid];
  __syncthreads();

  const int lane = tid & 63;
  const int g = lane >> 3;      // group 0..7
  const int r8 = lane & 7;      // row-in-group for scoring; d-eighth for acc
  const int wave = tid >> 6;    // k-quarter owner
  const int rowbase = blockIdx.x * 64 + g * 8;
  const int myrow = rowbase + r8;
  const int b = myrow >> 11;    // uniform per block (64-row span, 64|2048)

  const float pos = tsteps[myrow];
  const float divs[8] = {1.0f, 0.74989421f, 0.56234133f, 0.42169650f,
                         0.31622777f, 0.23713737f, 0.17782794f, 0.13335214f};
  float emb[NE];
#pragma unroll
  for (int m = 0; m < 8; ++m) {
    float a = 48.0f * pos * divs[m];
    emb[2 * m] = sinf(a);
    emb[2 * m + 1] = cosf(a);
  }
  float q[NE];
#pragma unroll
  for (int e = 0; e < NE; ++e) {
    float acc = bqs[e];
#pragma unroll
    for (int i = 0; i < NE; ++i) acc += emb[i] * wqs[e * NE + i];
    q[e] = acc * (0.25f * LOG2E);  // fold 1/sqrt(E) and log2e (exp2 direct)
  }
  const int pbase = tid & ~7;  // wave*64 + group's lane 0
  const float* __restrict__ vb = val + (size_t)b * NK * 64;

  float acc[8][8];
#pragma unroll
  for (int m = 0; m < 8; ++m)
#pragma unroll
    for (int d = 0; d < 8; ++d) acc[m][d] = 0.f;
  float lsum = 0.f;

#pragma unroll
  for (int kb = 0; kb < 2; ++kb) {
    const int khi = (wave << 1) | kb;   // this wave's k-block (uniform)
#pragma unroll 2
    for (int i = 0; i < 64; ++i) {
      const int ii = (i + g * 8) & 63;  // group stagger: distinct rows/instr
      const int k = (khi << 6) | ii;
      const float4* kr = (const float4*)(ktab + (size_t)k * NE);
      const float4 k0 = kr[0], k1 = kr[1], k2 = kr[2], k3 = kr[3];
      float s;
      s  = q[0] * k0.x + q[1] * k0.y + q[2] * k0.z + q[3] * k0.w;
      s += q[4] * k1.x + q[5] * k1.y + q[6] * k1.z + q[7] * k1.w;
      s += q[8] * k2.x + q[9] * k2.y + q[10] * k2.z + q[11] * k2.w;
      s += q[12] * k3.x + q[13] * k3.y + q[14] * k3.z + q[15] * k3.w;
      const float p = __builtin_amdgcn_exp2f(s);  // scores O(1): no max-sub
      lsum += p;
      // p-share: 1 write + 2 broadcast b128 reads (same-wave in-order LDS);
      // group lanes read identical 32 B (broadcast); groups 2-way alias = free
      pbuf[tid] = p;
      const float4 pq0 = *(const float4*)&pbuf[pbase];
      const float4 pq1 = *(const float4*)&pbuf[pbase + 4];
      const float* vr = vb + (size_t)k * 64 + r8 * 8;
      const float4 va = *(const float4*)(vr);
      const float4 vb4 = *(const float4*)(vr + 4);
      const float pm[8] = {pq0.x, pq0.y, pq0.z, pq0.w,
                           pq1.x, pq1.y, pq1.z, pq1.w};
#pragma unroll
      for (int m = 0; m < 8; ++m) {
        acc[m][0] += pm[m] * va.x;  acc[m][1] += pm[m] * va.y;
        acc[m][2] += pm[m] * va.z;  acc[m][3] += pm[m] * va.w;
        acc[m][4] += pm[m] * vb4.x; acc[m][5] += pm[m] * vb4.y;
        acc[m][6] += pm[m] * vb4.z; acc[m][7] += pm[m] * vb4.w;
      }
    }
  }

  // cross-wave combine: 4 partials per (row, dim); lsum totals once.
  const int lb = lane & ~7;
  lbuf[wave][lane] = lsum;
  float lt = 0.f;
  float* ob = att + (size_t)rowbase * 64 + r8 * 8;
#pragma unroll
  for (int mm = 0; mm < 8; mm += 2) {
    *(float4*)&cbuf[wave][lane][0] =
        make_float4(acc[mm][0], acc[mm][1], acc[mm][2], acc[mm][3]);
    *(float4*)&cbuf[wave][lane][4] =
        make_float4(acc[mm][4], acc[mm][5], acc[mm][6], acc[mm][7]);
    *(float4*)&cbuf[wave][lane][8] =
        make_float4(acc[mm + 1][0], acc[mm + 1][1], acc[mm + 1][2],
                    acc[mm + 1][3]);
    *(float4*)&cbuf[wave][lane][12] =
        make_float4(acc[mm + 1][4], acc[mm + 1][5], acc[mm + 1][6],
                    acc[mm + 1][7]);
    __syncthreads();
    if (mm == 0)
      lt = lbuf[0][lane] + lbuf[1][lane] + lbuf[2][lane] + lbuf[3][lane];
    if (wave == 0) {
      float s[16];
#pragma unroll
      for (int d4 = 0; d4 < 4; ++d4) {
        const float4 c0 = *(const float4*)&cbuf[0][lane][d4 * 4];
        const float4 c1 = *(const float4*)&cbuf[1][lane][d4 * 4];
        const float4 c2 = *(const float4*)&cbuf[2][lane][d4 * 4];
        const float4 c3 = *(const float4*)&cbuf[3][lane][d4 * 4];
        s[d4 * 4 + 0] = c0.x + c1.x + c2.x + c3.x;
        s[d4 * 4 + 1] = c0.y + c1.y + c2.y + c3.y;
        s[d4 * 4 + 2] = c0.z + c1.z + c2.z + c3.z;
        s[d4 * 4 + 3] = c0.w + c1.w + c2.w + c3.w;
      }
      const float im0 = 1.0f / bperm(lb + mm, lt);
      const float im1 = 1.0f / bperm(lb + mm + 1, lt);
      *(float4*)(ob + mm * 64) =
          make_float4(s[0] * im0, s[1] * im0, s[2] * im0, s[3] * im0);
      *(float4*)(ob + mm * 64 + 4) =
          make_float4(s[4] * im0, s[5] * im0, s[6] * im0, s[7] * im0);
      *(float4*)(ob + (mm + 1) * 64) =
          make_float4(s[8] * im1, s[9] * im1, s[10] * im1, s[11] * im1);
      *(float4*)(ob + (mm + 1) * 64 + 4) =
          make_float4(s[12] * im1, s[13] * im1, s[14] * im1, s[15] * im1);
    }
    __syncthreads();
  }
}

// Per-row MLP on folded weights, DS-lean: h[50] in regs, W2 rows padded to
// 52 floats and read as float4 (41x13 b128 instead of 2050 scalar reads).
__global__ __launch_bounds__(256) void mlp_kernel(
    const float* __restrict__ att,
    const float* __restrict__ w1p, const float* __restrict__ b1p,
    const float* __restrict__ W2, const float* __restrict__ b2,
    float* __restrict__ out) {
  __shared__ __align__(16) float w1s[NHID * 64];   // 12.8 KB
  __shared__ __align__(16) float w2s[NO * 52];     // 8.5 KB, 52-padded rows
  __shared__ float b1s[NHID], b2s[NO];
  const int tid = threadIdx.x;
  for (int i = tid; i < NHID * 64; i += 256) w1s[i] = w1p[i];
  for (int i = tid; i < NO * 52; i += 256) {
    const int oo = i / 52, o = i - oo * 52;
    w2s[i] = (o < NHID) ? W2[oo * NHID + o] : 0.f;
  }
  if (tid < NHID) b1s[tid] = b1p[tid];
  if (tid < NO) b2s[tid] = b2[tid];
  __syncthreads();

  const int row = blockIdx.x * 256 + tid;
  float ar[64];
  const float4* a4 = (const float4*)(att + (size_t)row * 64);
#pragma unroll
  for (int d4 = 0; d4 < 16; ++d4) {
    float4 v = a4[d4];
    ar[d4 * 4 + 0] = v.x;
    ar[d4 * 4 + 1] = v.y;
    ar[d4 * 4 + 2] = v.z;
    ar[d4 * 4 + 3] = v.w;
  }
  float h[52];
#pragma unroll 2
  for (int o = 0; o < NHID; ++o) {
    float acc = b1s[o];
    const float4* w4 = (const float4*)&w1s[o * 64];
#pragma unroll
    for (int i4 = 0; i4 < 16; ++i4) {
      float4 ww = w4[i4];
      acc += ar[i4 * 4 + 0] * ww.x + ar[i4 * 4 + 1] * ww.y +
             ar[i4 * 4 + 2] * ww.z + ar[i4 * 4 + 3] * ww.w;
    }
    h[o] = fmaxf(acc, 0.f);
  }
  h[50] = 0.f;
  h[51] = 0.f;
  float* orow = out + (size_t)row * NO;
#pragma unroll 2
  for (int oo = 0; oo < NO; ++oo) {
    float acc = b2s[oo];
    const float4* w4 = (const float4*)&w2s[oo * 52];
#pragma unroll
    for (int i4 = 0; i4 < 13; ++i4) {
      float4 ww = w4[i4];
      acc += h[i4 * 4 + 0] * ww.x + h[i4 * 4 + 1] * ww.y +
             h[i4 * 4 + 2] * ww.z + h[i4 * 4 + 3] * ww.w;
    }
    orow[oo] = acc;
  }
}

extern "C" void kernel_launch(void* const* d_in, const int* in_sizes, int n_in,
                              void* d_out, int out_size, void* d_ws, size_t ws_size,
                              hipStream_t stream) {
  const float* z = (const float*)d_in[0];
  const float* ts = (const float*)d_in[1];
  const float* refq = (const float*)d_in[2];
  const float* Wih_f = (const float*)d_in[3];
  const float* Whh_f = (const float*)d_in[4];
  const float* bih_f = (const float*)d_in[5];
  const float* bhh_f = (const float*)d_in[6];
  const float* Wih_b = (const float*)d_in[7];
  const float* Whh_b = (const float*)d_in[8];
  const float* bih_b = (const float*)d_in[9];
  const float* bhh_b = (const float*)d_in[10];
  const float* Wq = (const float*)d_in[11];
  const float* bq = (const float*)d_in[12];
  const float* Wk = (const float*)d_in[13];
  const float* bk = (const float*)d_in[14];
  const float* Wv = (const float*)d_in[15];
  const float* bv = (const float*)d_in[16];
  const float* W1 = (const float*)d_in[17];
  const float* b1 = (const float*)d_in[18];
  const float* W2 = (const float*)d_in[19];
  const float* b2 = (const float*)d_in[20];

  float* ws = (float*)d_ws;
  float* gi = ws;               // 3,145,728 (overlaid with att)
  float* att = ws;              // 4,194,304
  float* val = ws + 4194304;    // 1,048,576
  float* ktab = ws + 5242880;   // 8,192
  float* w1p = ws + 5251072;    // 3,200
  float* b1p = ws + 5254272;    // 64
  float* out = (float*)d_out;

  prep_kernel<<<3, 256, 0, stream>>>(refq, Wk, bk, Wv, bv, W1, b1,
                                     ktab, w1p, b1p);
  prep_gi_kernel<<<128, 256, 0, stream>>>(z, Wih_f, bih_f, bhh_f,
                                          Wih_b, bih_b, bhh_b, gi);
  gru_kernel<<<32, 64, 0, stream>>>(gi, Whh_f, bhh_f, Whh_b, bhh_b, val);
  attn_core_kernel<<<1024, 256, 0, stream>>>(ts, ktab, val, Wq, bq, att);
  mlp_kernel<<<256, 256, 0, stream>>>(att, w1p, b1p, W2, b2, out);
}

// Round 16
// 348.267 us; speedup vs baseline: 1.2797x; 1.0007x over previous
//
#include <hip/hip_runtime.h>
#include <hip/hip_bf16.h>
#include <math.h>

#define NB 32
#define NQ 2048
#define NK 512
#define NE 16
#define NH 32
#define NL 20
#define NHID 50
#define NO 41

#define LOG2E 1.4426950408889634f
#define TWO_LOG2E 2.8853900817779268f

// ws layout (floats):
// gi   : [64][512][96] @ 0        (3,145,728)  OVERLAID with att (gru before attn)
// att  : [65536][64]   @ 0        (4,194,304)  normalized P@val (pre-Wv)
// val  : [32][512][64] @ 4194304  (1,048,576)
// ktab : [512][16]     @ 5242880  (8,192)
// w1p  : [50][64]      @ 5251072  (3,200)      W1 @ Wv
// b1p  : [50]          @ 5254272  (64)         b1 + W1 @ bv
// total ~21.0 MB (proven size)

typedef __attribute__((ext_vector_type(2))) float f32x2;

__device__ __forceinline__ float bperm(int lane, float v) {
  return __builtin_bit_cast(
      float, __builtin_amdgcn_ds_bpermute(lane << 2, __builtin_bit_cast(int, v)));
}

// blocks 0-1: k-table. block 2: fold Wv into W1.
__global__ __launch_bounds__(256) void prep_kernel(
    const float* __restrict__ refq, const float* __restrict__ Wk,
    const float* __restrict__ bk,
    const float* __restrict__ Wv, const float* __restrict__ bv,
    const float* __restrict__ W1, const float* __restrict__ b1,
    float* __restrict__ ktab, float* __restrict__ w1p,
    float* __restrict__ b1p) {
  const int tid = threadIdx.x;
  if (blockIdx.x < 2) {
    const int r = blockIdx.x * 256 + tid;
    const float divs[8] = {1.0f, 0.74989421f, 0.56234133f, 0.42169650f,
                           0.31622777f, 0.23713737f, 0.17782794f, 0.13335214f};
    float pos = refq[r];
    float emb[NE];
#pragma unroll
    for (int m = 0; m < 8; ++m) {
      float a = 48.0f * pos * divs[m];
      emb[2 * m] = sinf(a);
      emb[2 * m + 1] = cosf(a);
    }
#pragma unroll
    for (int e = 0; e < NE; ++e) {
      float acc = bk[e];
#pragma unroll
      for (int i = 0; i < NE; ++i) acc += emb[i] * Wk[e * NE + i];
      ktab[r * NE + e] = acc;
    }
  } else {
    for (int e = tid; e < NHID * 64; e += 256) {
      const int o = e >> 6, i = e & 63;
      float acc = 0.f;
#pragma unroll 4
      for (int d = 0; d < 64; ++d) acc += W1[o * 64 + d] * Wv[d * 64 + i];
      w1p[e] = acc;
    }
    if (tid < NHID) {
      float acc = b1[tid];
#pragma unroll 4
      for (int d = 0; d < 64; ++d) acc += W1[tid * 64 + d] * bv[d];
      b1p[tid] = acc;
    }
  }
}

// Input-side gates, fully parallel; pre-scaled for exp2-based activations.
__global__ __launch_bounds__(256) void prep_gi_kernel(
    const float* __restrict__ z,
    const float* __restrict__ Wih_f, const float* __restrict__ bih_f,
    const float* __restrict__ bhh_f,
    const float* __restrict__ Wih_b, const float* __restrict__ bih_b,
    const float* __restrict__ bhh_b, float* __restrict__ gi) {
  const int row = blockIdx.x * 256 + threadIdx.x;  // chain*512 + t
  const int c = row >> 9, t = row & 511;
  const int dir = c >> 5, b = c & 31;
  const float* __restrict__ Wih = dir ? Wih_b : Wih_f;
  const float* __restrict__ bih = dir ? bih_b : bih_f;
  const float* __restrict__ bhh = dir ? bhh_b : bhh_f;
  const float* __restrict__ zr = z + ((size_t)b * NK + t) * NL;
  float x[NL];
#pragma unroll
  for (int i = 0; i < NL; ++i) x[i] = zr[i];
  float* __restrict__ go = gi + (size_t)row * 96;
  for (int g = 0; g < 96; ++g) {
    float acc = bih[g] + (g < 64 ? bhh[g] : 0.f);
#pragma unroll
    for (int i = 0; i < NL; ++i) acc += x[i] * Wih[g * NL + i];
    go[g] = acc * (g < 64 ? LOG2E : TWO_LOG2E);
  }
}

// Serial GRU (round-13, PASSED at 134 us): 2 chains per wave, full 32-dots,
// ONE DS round per step, exp2-folded activations, pk-FMA, pointer-walked IO.
__global__ __launch_bounds__(64) void gru_kernel(
    const float* __restrict__ gi,
    const float* __restrict__ Whh_f, const float* __restrict__ bhh_f,
    const float* __restrict__ Whh_b, const float* __restrict__ bhh_b,
    float* __restrict__ val) {
  __shared__ __align__(16) float hbuf[64];  // [chain-half][32]
  const int l = threadIdx.x;
  const int j = l & 31, half = l >> 5;
  const int c = blockIdx.x * 2 + half;   // 2|32 => both halves same dir
  const int dir = c >> 5, b = c & 31;
  const int hb = half * 32;
  const float* __restrict__ Whh = dir ? Whh_b : Whh_f;
  const float* __restrict__ bhh = dir ? bhh_b : bhh_f;

  // weights pre-scaled: r,z x log2e; n x 2*log2e (gi scaled to match)
  f32x2 wr[16], wz[16], wn[16];
#pragma unroll
  for (int i = 0; i < 16; ++i) {
    wr[i] = f32x2{Whh[j * 32 + 2 * i], Whh[j * 32 + 2 * i + 1]} * LOG2E;
    wz[i] = f32x2{Whh[(j + 32) * 32 + 2 * i], Whh[(j + 32) * 32 + 2 * i + 1]} *
            LOG2E;
    wn[i] = f32x2{Whh[(j + 64) * 32 + 2 * i], Whh[(j + 64) * 32 + 2 * i + 1]} *
            TWO_LOG2E;
  }
  const float bhn = bhh[j + 64] * TWO_LOG2E;
  float h = 0.f;
  hbuf[l] = 0.f;

  const float* __restrict__ gic = gi + (size_t)c * NK * 96;
  const int gstart = dir ? (NK - 1) * 96 : 0;
  const int gstride = dir ? -96 : 96;
  float* __restrict__ vp =
      val + ((size_t)b * NK + (dir ? NK - 1 : 0)) * 64 + dir * 32 + j;
  const int vstride = dir ? -64 : 64;

  float r0, z0, n0, r1, z1, n1, r2, z2, n2, r3, z3, n3;
  int gidx = gstart;
  auto giload = [&](float& gr, float& gz, float& gn) {
    const float* p = gic + gidx;
    gr = p[j];
    gz = p[32 + j];
    gn = p[64 + j];
    gidx += gstride;
  };
  giload(r0, z0, n0);
  giload(r1, z1, n1);
  giload(r2, z2, n2);
  giload(r3, z3, n3);

  auto step = [&](bool pf, float& gr, float& gz, float& gn) {
    const float gir = gr, giz = gz, gin = gn;
    if (pf) giload(gr, gz, gn);  // global prefetch (vmcnt queue)
    hbuf[l] = h;  // same-wave LDS is in-order (proven rounds 4-15)
    f32x2 hv[16];
#pragma unroll
    for (int t = 0; t < 4; ++t) {
      const float4 hq = *(const float4*)&hbuf[hb + t * 8];
      const float4 hq2 = *(const float4*)&hbuf[hb + t * 8 + 4];
      hv[t * 4 + 0] = f32x2{hq.x, hq.y};
      hv[t * 4 + 1] = f32x2{hq.z, hq.w};
      hv[t * 4 + 2] = f32x2{hq2.x, hq2.y};
      hv[t * 4 + 3] = f32x2{hq2.z, hq2.w};
    }
    f32x2 sr2 = {0.f, 0.f}, sz2 = {0.f, 0.f}, sn2 = {0.f, 0.f};
    f32x2 sr3 = {0.f, 0.f}, sz3 = {0.f, 0.f}, sn3 = {0.f, 0.f};
#pragma unroll
    for (int t = 0; t < 8; ++t) {
      sr2 = __builtin_elementwise_fma(wr[t], hv[t], sr2);
      sz2 = __builtin_elementwise_fma(wz[t], hv[t], sz2);
      sn2 = __builtin_elementwise_fma(wn[t], hv[t], sn2);
      sr3 = __builtin_elementwise_fma(wr[8 + t], hv[8 + t], sr3);
      sz3 = __builtin_elementwise_fma(wz[8 + t], hv[8 + t], sz3);
      sn3 = __builtin_elementwise_fma(wn[8 + t], hv[8 + t], sn3);
    }
    const float sr = (sr2.x + sr2.y) + (sr3.x + sr3.y);
    const float sz = (sz2.x + sz2.y) + (sz3.x + sz3.y);
    const float sn = (sn2.x + sn2.y) + (sn3.x + sn3.y);
    const float rg =
        __builtin_amdgcn_rcpf(1.0f + __builtin_amdgcn_exp2f(-(gir + sr)));
    const float ug =
        __builtin_amdgcn_rcpf(1.0f + __builtin_amdgcn_exp2f(-(giz + sz)));
    const float ng =
        1.0f - 2.0f * __builtin_amdgcn_rcpf(
                          __builtin_amdgcn_exp2f(gin + rg * (sn + bhn)) + 1.0f);
    h = ng + ug * (h - ng);
    *vp = h;
    vp += vstride;
  };
  for (int s = 0; s < NK; s += 4) {
    step(s + 4 < NK, r0, z0, n0);
    step(s + 5 < NK, r1, z1, n1);
    step(s + 6 < NK, r2, z2, n2);
    step(s + 7 < NK, r3, z3, n3);
  }
}

// R=8 attention v5: 8 waves per block (512 thr), wave w owns k-block khi=w
// (64 keys); packed dual-FMA (v_pk_fma_f32) for scores and accumulation;
// p-share via per-wave LDS slot (r15-proven); 8-partial LDS combine.
// 32 waves/CU (4 blocks x 8 waves) doubles the issue-packing pool.
__global__ __launch_bounds__(512) void attn_core_kernel(
    const float* __restrict__ tsteps, const float* __restrict__ ktab,
    const float* __restrict__ val,
    const float* __restrict__ Wq, const float* __restrict__ bq,
    float* __restrict__ att) {
  __shared__ __align__(16) float cbuf[8][64][16];    // 32 KB combine buffer
  __shared__ __align__(16) float pbuf[512];          // 2 KB p-share
  __shared__ float lbuf[8][64];                      // 2 KB lsum partials
  __shared__ float wqs[NE * NE];
  __shared__ float bqs[NE];
  const int tid = threadIdx.x;
  for (int i = tid; i < NE * NE; i += 512) wqs[i] = Wq[i];
  if (tid < NE) bqs[tid] = bq[tid];
  __syncthreads();

  const int lane = tid & 63;
  const int g = lane >> 3;      // group 0..7
  const int r8 = lane & 7;      // row-in-group for scoring; d-eighth for acc
  const int wave = tid >> 6;    // k-eighth owner (khi = wave)
  const int rowbase = blockIdx.x * 64 + g * 8;
  const int myrow = rowbase + r8;
  const int b = myrow >> 11;    // uniform per block (64-row span, 64|2048)

  const float pos = tsteps[myrow];
  const float divs[8] = {1.0f, 0.74989421f, 0.56234133f, 0.42169650f,
                         0.31622777f, 0.23713737f, 0.17782794f, 0.13335214f};
  float emb[NE];
#pragma unroll
  for (int m = 0; m < 8; ++m) {
    float a = 48.0f * pos * divs[m];
    emb[2 * m] = sinf(a);
    emb[2 * m + 1] = cosf(a);
  }
  f32x2 q2[8];
#pragma unroll
  for (int e = 0; e < 8; ++e) {
    float a0 = bqs[2 * e], a1 = bqs[2 * e + 1];
#pragma unroll
    for (int i = 0; i < NE; ++i) {
      a0 += emb[i] * wqs[(2 * e) * NE + i];
      a1 += emb[i] * wqs[(2 * e + 1) * NE + i];
    }
    q2[e] = f32x2{a0, a1} * (0.25f * LOG2E);  // fold 1/sqrt(E), log2e
  }
  const int pbase = tid & ~7;  // this wave's group slot in pbuf
  const float* __restrict__ vb = val + (size_t)b * NK * 64;

  f32x2 acc2[8][4];
#pragma unroll
  for (int m = 0; m < 8; ++m)
#pragma unroll
    for (int d = 0; d < 4; ++d) acc2[m][d] = f32x2{0.f, 0.f};
  float lsum = 0.f;

  const int khi = wave;  // this wave's 64-key block
#pragma unroll 2
  for (int i = 0; i < 64; ++i) {
    const int ii = (i + g * 8) & 63;  // group stagger: distinct rows/instr
    const int k = (khi << 6) | ii;
    const float4* kr = (const float4*)(ktab + (size_t)k * NE);
    const float4 k0 = kr[0], k1 = kr[1], k2 = kr[2], k3 = kr[3];
    f32x2 s2 = {0.f, 0.f};
    s2 = __builtin_elementwise_fma(q2[0], f32x2{k0.x, k0.y}, s2);
    s2 = __builtin_elementwise_fma(q2[1], f32x2{k0.z, k0.w}, s2);
    s2 = __builtin_elementwise_fma(q2[2], f32x2{k1.x, k1.y}, s2);
    s2 = __builtin_elementwise_fma(q2[3], f32x2{k1.z, k1.w}, s2);
    s2 = __builtin_elementwise_fma(q2[4], f32x2{k2.x, k2.y}, s2);
    s2 = __builtin_elementwise_fma(q2[5], f32x2{k2.z, k2.w}, s2);
    s2 = __builtin_elementwise_fma(q2[6], f32x2{k3.x, k3.y}, s2);
    s2 = __builtin_elementwise_fma(q2[7], f32x2{k3.z, k3.w}, s2);
    const float p = __builtin_amdgcn_exp2f(s2.x + s2.y);  // O(1): no max-sub
    lsum += p;
    // p-share: 1 write + 2 broadcast b128 reads (same-wave in-order LDS)
    pbuf[tid] = p;
    const float4 pq0 = *(const float4*)&pbuf[pbase];
    const float4 pq1 = *(const float4*)&pbuf[pbase + 4];
    const float* vr = vb + (size_t)k * 64 + r8 * 8;
    const float4 va = *(const float4*)(vr);
    const float4 vb4 = *(const float4*)(vr + 4);
    const f32x2 v2[4] = {f32x2{va.x, va.y}, f32x2{va.z, va.w},
                         f32x2{vb4.x, vb4.y}, f32x2{vb4.z, vb4.w}};
    const float pm[8] = {pq0.x, pq0.y, pq0.z, pq0.w,
                         pq1.x, pq1.y, pq1.z, pq1.w};
#pragma unroll
    for (int m = 0; m < 8; ++m) {
      const f32x2 pm2 = {pm[m], pm[m]};
      acc2[m][0] = __builtin_elementwise_fma(pm2, v2[0], acc2[m][0]);
      acc2[m][1] = __builtin_elementwise_fma(pm2, v2[1], acc2[m][1]);
      acc2[m][2] = __builtin_elementwise_fma(pm2, v2[2], acc2[m][2]);
      acc2[m][3] = __builtin_elementwise_fma(pm2, v2[3], acc2[m][3]);
    }
  }

  // cross-wave combine: 8 partials per (row, dim); lsum totals once.
  const int lb = lane & ~7;
  lbuf[wave][lane] = lsum;
  float lt = 0.f;
  float* ob = att + (size_t)rowbase * 64 + r8 * 8;
#pragma unroll
  for (int mm = 0; mm < 8; mm += 2) {
    *(float4*)&cbuf[wave][lane][0] =
        make_float4(acc2[mm][0].x, acc2[mm][0].y, acc2[mm][1].x, acc2[mm][1].y);
    *(float4*)&cbuf[wave][lane][4] =
        make_float4(acc2[mm][2].x, acc2[mm][2].y, acc2[mm][3].x, acc2[mm][3].y);
    *(float4*)&cbuf[wave][lane][8] =
        make_float4(acc2[mm + 1][0].x, acc2[mm + 1][0].y, acc2[mm + 1][1].x,
                    acc2[mm + 1][1].y);
    *(float4*)&cbuf[wave][lane][12] =
        make_float4(acc2[mm + 1][2].x, acc2[mm + 1][2].y, acc2[mm + 1][3].x,
                    acc2[mm + 1][3].y);
    __syncthreads();
    if (mm == 0) {
      lt = 0.f;
#pragma unroll
      for (int w = 0; w < 8; ++w) lt += lbuf[w][lane];
    }
    if (wave == 0) {
      float s[16];
#pragma unroll
      for (int d4 = 0; d4 < 4; ++d4) {
        float4 c = *(const float4*)&cbuf[0][lane][d4 * 4];
        float s0 = c.x, s1 = c.y, s2v = c.z, s3 = c.w;
#pragma unroll
        for (int w = 1; w < 8; ++w) {
          const float4 cw = *(const float4*)&cbuf[w][lane][d4 * 4];
          s0 += cw.x; s1 += cw.y; s2v += cw.z; s3 += cw.w;
        }
        s[d4 * 4 + 0] = s0;
        s[d4 * 4 + 1] = s1;
        s[d4 * 4 + 2] = s2v;
        s[d4 * 4 + 3] = s3;
      }
      const float im0 = 1.0f / bperm(lb + mm, lt);
      const float im1 = 1.0f / bperm(lb + mm + 1, lt);
      *(float4*)(ob + mm * 64) =
          make_float4(s[0] * im0, s[1] * im0, s[2] * im0, s[3] * im0);
      *(float4*)(ob + mm * 64 + 4) =
          make_float4(s[4] * im0, s[5] * im0, s[6] * im0, s[7] * im0);
      *(float4*)(ob + (mm + 1) * 64) =
          make_float4(s[8] * im1, s[9] * im1, s[10] * im1, s[11] * im1);
      *(float4*)(ob + (mm + 1) * 64 + 4) =
          make_float4(s[12] * im1, s[13] * im1, s[14] * im1, s[15] * im1);
    }
    __syncthreads();
  }
}

// Per-row MLP on folded weights, DS-lean (r15-proven).
__global__ __launch_bounds__(256) void mlp_kernel(
    const float* __restrict__ att,
    const float* __restrict__ w1p, const float* __restrict__ b1p,
    const float* __restrict__ W2, const float* __restrict__ b2,
    float* __restrict__ out) {
  __shared__ __align__(16) float w1s[NHID * 64];   // 12.8 KB
  __shared__ __align__(16) float w2s[NO * 52];     // 8.5 KB, 52-padded rows
  __shared__ float b1s[NHID], b2s[NO];
  const int tid = threadIdx.x;
  for (int i = tid; i < NHID * 64; i += 256) w1s[i] = w1p[i];
  for (int i = tid; i < NO * 52; i += 256) {
    const int oo = i / 52, o = i - oo * 52;
    w2s[i] = (o < NHID) ? W2[oo * NHID + o] : 0.f;
  }
  if (tid < NHID) b1s[tid] = b1p[tid];
  if (tid < NO) b2s[tid] = b2[tid];
  __syncthreads();

  const int row = blockIdx.x * 256 + tid;
  float ar[64];
  const float4* a4 = (const float4*)(att + (size_t)row * 64);
#pragma unroll
  for (int d4 = 0; d4 < 16; ++d4) {
    float4 v = a4[d4];
    ar[d4 * 4 + 0] = v.x;
    ar[d4 * 4 + 1] = v.y;
    ar[d4 * 4 + 2] = v.z;
    ar[d4 * 4 + 3] = v.w;
  }
  float h[52];
#pragma unroll 2
  for (int o = 0; o < NHID; ++o) {
    float acc = b1s[o];
    const float4* w4 = (const float4*)&w1s[o * 64];
#pragma unroll
    for (int i4 = 0; i4 < 16; ++i4) {
      float4 ww = w4[i4];
      acc += ar[i4 * 4 + 0] * ww.x + ar[i4 * 4 + 1] * ww.y +
             ar[i4 * 4 + 2] * ww.z + ar[i4 * 4 + 3] * ww.w;
    }
    h[o] = fmaxf(acc, 0.f);
  }
  h[50] = 0.f;
  h[51] = 0.f;
  float* orow = out + (size_t)row * NO;
#pragma unroll 2
  for (int oo = 0; oo < NO; ++oo) {
    float acc = b2s[oo];
    const float4* w4 = (const float4*)&w2s[oo * 52];
#pragma unroll
    for (int i4 = 0; i4 < 13; ++i4) {
      float4 ww = w4[i4];
      acc += h[i4 * 4 + 0] * ww.x + h[i4 * 4 + 1] * ww.y +
             h[i4 * 4 + 2] * ww.z + h[i4 * 4 + 3] * ww.w;
    }
    orow[oo] = acc;
  }
}

extern "C" void kernel_launch(void* const* d_in, const int* in_sizes, int n_in,
                              void* d_out, int out_size, void* d_ws, size_t ws_size,
                              hipStream_t stream) {
  const float* z = (const float*)d_in[0];
  const float* ts = (const float*)d_in[1];
  const float* refq = (const float*)d_in[2];
  const float* Wih_f = (const float*)d_in[3];
  const float* Whh_f = (const float*)d_in[4];
  const float* bih_f = (const float*)d_in[5];
  const float* bhh_f = (const float*)d_in[6];
  const float* Wih_b = (const float*)d_in[7];
  const float* Whh_b = (const float*)d_in[8];
  const float* bih_b = (const float*)d_in[9];
  const float* bhh_b = (const float*)d_in[10];
  const float* Wq = (const float*)d_in[11];
  const float* bq = (const float*)d_in[12];
  const float* Wk = (const float*)d_in[13];
  const float* bk = (const float*)d_in[14];
  const float* Wv = (const float*)d_in[15];
  const float* bv = (const float*)d_in[16];
  const float* W1 = (const float*)d_in[17];
  const float* b1 = (const float*)d_in[18];
  const float* W2 = (const float*)d_in[19];
  const float* b2 = (const float*)d_in[20];

  float* ws = (float*)d_ws;
  float* gi = ws;               // 3,145,728 (overlaid with att)
  float* att = ws;              // 4,194,304
  float* val = ws + 4194304;    // 1,048,576
  float* ktab = ws + 5242880;   // 8,192
  float* w1p = ws + 5251072;    // 3,200
  float* b1p = ws + 5254272;    // 64
  float* out = (float*)d_out;

  prep_kernel<<<3, 256, 0, stream>>>(refq, Wk, bk, Wv, bv, W1, b1,
                                     ktab, w1p, b1p);
  prep_gi_kernel<<<128, 256, 0, stream>>>(z, Wih_f, bih_f, bhh_f,
                                          Wih_b, bih_b, bhh_b, gi);
  gru_kernel<<<32, 64, 0, stream>>>(gi, Whh_f, bhh_f, Whh_b, bhh_b, val);
  attn_core_kernel<<<1024, 512, 0, stream>>>(ts, ktab, val, Wq, bq, att);
  mlp_kernel<<<256, 256, 0, stream>>>(att, w1p, b1p, W2, b2, out);
}